// Round 4
// baseline (373.975 us; speedup 1.0000x reference)
//
#include <hip/hip_runtime.h>
#include <math.h>

#define N_NODES 10000
#define PAD_N   10048
#define N_EDGES 160000
#define ET      (N_EDGES + N_NODES)   // with self loops

typedef unsigned short u16;
typedef __attribute__((ext_vector_type(8))) short bf16x8;
typedef __attribute__((ext_vector_type(4))) float f32x4;

__device__ __forceinline__ u16 f2bf(float f) {
    union { float f; unsigned u; } v; v.f = f;
    unsigned r = (v.u + 0x7FFFu + ((v.u >> 16) & 1u)) >> 16;
    return (u16)r;
}
__device__ __forceinline__ float bf2f(u16 b) {
    union { unsigned u; float f; } v; v.u = ((unsigned)b) << 16;
    return v.f;
}

// ---------------------------------------------------------------------------
// fp32 -> bf16 hi/lo split (same layout), vectorized by 4
// ---------------------------------------------------------------------------
__global__ void split_kernel(const float* __restrict__ in, u16* __restrict__ hi,
                             u16* __restrict__ lo, int n4) {
    int i = blockIdx.x * blockDim.x + threadIdx.x;
    if (i >= n4) return;
    float4 v = reinterpret_cast<const float4*>(in)[i];
    u16 h0 = f2bf(v.x), h1 = f2bf(v.y), h2 = f2bf(v.z), h3 = f2bf(v.w);
    ushort4 hv = make_ushort4(h0, h1, h2, h3);
    ushort4 lv = make_ushort4(f2bf(v.x - bf2f(h0)), f2bf(v.y - bf2f(h1)),
                              f2bf(v.z - bf2f(h2)), f2bf(v.w - bf2f(h3)));
    reinterpret_cast<ushort4*>(hi)[i] = hv;
    reinterpret_cast<ushort4*>(lo)[i] = lv;
}

// ---------------------------------------------------------------------------
// weight split + transpose: W[K][N] fp32 -> th/tl[N][K] bf16
// ---------------------------------------------------------------------------
__global__ void wsplit_kernel(const float* __restrict__ W, u16* __restrict__ th,
                              u16* __restrict__ tl, int K, int N) {
    int idx = blockIdx.x * blockDim.x + threadIdx.x;
    if (idx >= K * N) return;
    int k = idx / N, n = idx - k * N;
    float v = W[idx];
    u16 h = f2bf(v);
    th[(size_t)n * K + k] = h;
    tl[(size_t)n * K + k] = f2bf(v - bf2f(h));
}

// ---------------------------------------------------------------------------
// va1[k][h] = sum_c W1[k, h*128+c] * att_src[h][c]  (and same with att_dst)
// Folds the gat1 attention projection so h1 never materializes.
// 1 block x 512 threads, thread = k*4+h.
// ---------------------------------------------------------------------------
__global__ void va1_kernel(const float* __restrict__ W1,
                           const float* __restrict__ att_src,
                           const float* __restrict__ att_dst,
                           float* __restrict__ vas, float* __restrict__ vad) {
    int tid = threadIdx.x;
    int k = tid >> 2, h = tid & 3;
    float s = 0.0f, d = 0.0f;
    const float* wr = W1 + (size_t)k * 512 + h * 128;
    const float* as = att_src + h * 128;
    const float* ad = att_dst + h * 128;
    for (int c = 0; c < 128; ++c) {
        float w = wr[c];
        s = fmaf(w, as[c], s);
        d = fmaf(w, ad[c], d);
    }
    vas[k * 4 + h] = s;
    vad[k * 4 + h] = d;
}

// ---------------------------------------------------------------------------
// gat1 attention logits from xp: as1[n,h] = sum_k xp[n,k]*vas[k,h]
// Wave per node (4 waves/block). lane covers k = lane*2, lane*2+1.
// ---------------------------------------------------------------------------
__global__ void att1_kernel(const float* __restrict__ xp,
                            const float* __restrict__ vas,
                            const float* __restrict__ vad,
                            float* __restrict__ as, float* __restrict__ ad) {
    int wv = threadIdx.x >> 6, lane = threadIdx.x & 63;
    int n = blockIdx.x * 4 + wv;
    float2 v = *reinterpret_cast<const float2*>(xp + (size_t)n * 128 + lane * 2);
    float4 s0 = *reinterpret_cast<const float4*>(vas + (lane * 2) * 4);
    float4 s1 = *reinterpret_cast<const float4*>(vas + (lane * 2 + 1) * 4);
    float4 d0 = *reinterpret_cast<const float4*>(vad + (lane * 2) * 4);
    float4 d1 = *reinterpret_cast<const float4*>(vad + (lane * 2 + 1) * 4);
    float ss[4] = { v.x * s0.x + v.y * s1.x, v.x * s0.y + v.y * s1.y,
                    v.x * s0.z + v.y * s1.z, v.x * s0.w + v.y * s1.w };
    float dd[4] = { v.x * d0.x + v.y * d1.x, v.x * d0.y + v.y * d1.y,
                    v.x * d0.z + v.y * d1.z, v.x * d0.w + v.y * d1.w };
#pragma unroll
    for (int m = 32; m > 0; m >>= 1)
#pragma unroll
        for (int h = 0; h < 4; ++h) {
            ss[h] += __shfl_xor(ss[h], m, 64);
            dd[h] += __shfl_xor(dd[h], m, 64);
        }
    if (lane == 0) {
#pragma unroll
        for (int h = 0; h < 4; ++h) {
            as[(size_t)n * 4 + h] = ss[h];
            ad[(size_t)n * 4 + h] = dd[h];
        }
    }
}

// ---------------------------------------------------------------------------
// Split-bf16 MFMA GEMM (as validated in round 2/3).
// OUTMODE 0: fp32 out. OUTMODE 1: bf16 hi/lo out.
// ---------------------------------------------------------------------------
template<int K, int NDIM, int OUTMODE>
__global__ __launch_bounds__(256, 4)
void mm_kernel(const u16* __restrict__ Ah, const u16* __restrict__ Al,
               const u16* __restrict__ Bh, const u16* __restrict__ Bl,
               const float* __restrict__ bias,
               float* __restrict__ outf, u16* __restrict__ outh, u16* __restrict__ outl,
               int arowmax) {
    int lane = threadIdx.x & 63;
    int wid  = threadIdx.x >> 6;
    int wm = wid >> 1, wn = wid & 1;
    int row0 = blockIdx.x * 64 + wm * 32;
    int col0 = blockIdx.y * 64 + wn * 32;
    int lr = lane & 15;
    int lk = (lane >> 4) * 8;

    int ra0 = min(row0 + lr,      arowmax);
    int ra1 = min(row0 + 16 + lr, arowmax);
    const u16* pa0h = Ah + (size_t)ra0 * K + lk;
    const u16* pa1h = Ah + (size_t)ra1 * K + lk;
    const u16* pa0l = Al + (size_t)ra0 * K + lk;
    const u16* pa1l = Al + (size_t)ra1 * K + lk;
    const u16* pb0h = Bh + (size_t)(col0 + lr)      * K + lk;
    const u16* pb1h = Bh + (size_t)(col0 + 16 + lr) * K + lk;
    const u16* pb0l = Bl + (size_t)(col0 + lr)      * K + lk;
    const u16* pb1l = Bl + (size_t)(col0 + 16 + lr) * K + lk;

    f32x4 acc[2][2];
#pragma unroll
    for (int i = 0; i < 2; ++i)
#pragma unroll
        for (int j = 0; j < 2; ++j) acc[i][j] = (f32x4){0.f, 0.f, 0.f, 0.f};

#pragma unroll 2
    for (int k = 0; k < K; k += 32) {
        bf16x8 a0h = *(const bf16x8*)(pa0h + k);
        bf16x8 a1h = *(const bf16x8*)(pa1h + k);
        bf16x8 a0l = *(const bf16x8*)(pa0l + k);
        bf16x8 a1l = *(const bf16x8*)(pa1l + k);
        bf16x8 b0h = *(const bf16x8*)(pb0h + k);
        bf16x8 b1h = *(const bf16x8*)(pb1h + k);
        bf16x8 b0l = *(const bf16x8*)(pb0l + k);
        bf16x8 b1l = *(const bf16x8*)(pb1l + k);

        acc[0][0] = __builtin_amdgcn_mfma_f32_16x16x32_bf16(a0h, b0h, acc[0][0], 0, 0, 0);
        acc[0][1] = __builtin_amdgcn_mfma_f32_16x16x32_bf16(a0h, b1h, acc[0][1], 0, 0, 0);
        acc[1][0] = __builtin_amdgcn_mfma_f32_16x16x32_bf16(a1h, b0h, acc[1][0], 0, 0, 0);
        acc[1][1] = __builtin_amdgcn_mfma_f32_16x16x32_bf16(a1h, b1h, acc[1][1], 0, 0, 0);
        acc[0][0] = __builtin_amdgcn_mfma_f32_16x16x32_bf16(a0h, b0l, acc[0][0], 0, 0, 0);
        acc[0][1] = __builtin_amdgcn_mfma_f32_16x16x32_bf16(a0h, b1l, acc[0][1], 0, 0, 0);
        acc[1][0] = __builtin_amdgcn_mfma_f32_16x16x32_bf16(a1h, b0l, acc[1][0], 0, 0, 0);
        acc[1][1] = __builtin_amdgcn_mfma_f32_16x16x32_bf16(a1h, b1l, acc[1][1], 0, 0, 0);
        acc[0][0] = __builtin_amdgcn_mfma_f32_16x16x32_bf16(a0l, b0h, acc[0][0], 0, 0, 0);
        acc[0][1] = __builtin_amdgcn_mfma_f32_16x16x32_bf16(a0l, b1h, acc[0][1], 0, 0, 0);
        acc[1][0] = __builtin_amdgcn_mfma_f32_16x16x32_bf16(a1l, b0h, acc[1][0], 0, 0, 0);
        acc[1][1] = __builtin_amdgcn_mfma_f32_16x16x32_bf16(a1l, b1h, acc[1][1], 0, 0, 0);
    }

    int orq = (lane >> 4) * 4;
#pragma unroll
    for (int fm = 0; fm < 2; ++fm)
#pragma unroll
        for (int fn = 0; fn < 2; ++fn) {
            int oc = col0 + fn * 16 + lr;
            float bb = bias ? bias[oc] : 0.0f;
#pragma unroll
            for (int i = 0; i < 4; ++i) {
                int orow = row0 + fm * 16 + orq + i;
                if (orow < N_NODES) {
                    float r = acc[fm][fn][i] + bb;
                    if (OUTMODE == 0) {
                        outf[(size_t)orow * NDIM + oc] = r;
                    } else {
                        u16 hh = f2bf(r);
                        outh[(size_t)orow * NDIM + oc] = hh;
                        outl[(size_t)orow * NDIM + oc] = f2bf(r - bf2f(hh));
                    }
                }
            }
        }
}

// ---------------------------------------------------------------------------
// Per-head post-aggregation GEMM (gat1):
// helu[n, head*128+oc] = elu( aggx[head][n][:] . W1t[head][oc][:] + b ) -> bf16 hi/lo
// grid (157, 2, 4=head); block 256.
// ---------------------------------------------------------------------------
__global__ __launch_bounds__(256, 4)
void mm_head_kernel(const u16* __restrict__ Ah, const u16* __restrict__ Al,
                    const u16* __restrict__ Bh, const u16* __restrict__ Bl,
                    const float* __restrict__ bias,
                    u16* __restrict__ outh, u16* __restrict__ outl) {
    constexpr int K = 128;
    int head = blockIdx.z;
    const u16* ah = Ah + (size_t)head * PAD_N * K;
    const u16* al = Al + (size_t)head * PAD_N * K;
    const u16* bh = Bh + (size_t)head * 128 * K;
    const u16* bl = Bl + (size_t)head * 128 * K;

    int lane = threadIdx.x & 63;
    int wid  = threadIdx.x >> 6;
    int wm = wid >> 1, wn = wid & 1;
    int row0 = blockIdx.x * 64 + wm * 32;
    int col0 = blockIdx.y * 64 + wn * 32;
    int lr = lane & 15;
    int lk = (lane >> 4) * 8;

    int ra0 = min(row0 + lr,      N_NODES - 1);
    int ra1 = min(row0 + 16 + lr, N_NODES - 1);
    const u16* pa0h = ah + (size_t)ra0 * K + lk;
    const u16* pa1h = ah + (size_t)ra1 * K + lk;
    const u16* pa0l = al + (size_t)ra0 * K + lk;
    const u16* pa1l = al + (size_t)ra1 * K + lk;
    const u16* pb0h = bh + (size_t)(col0 + lr)      * K + lk;
    const u16* pb1h = bh + (size_t)(col0 + 16 + lr) * K + lk;
    const u16* pb0l = bl + (size_t)(col0 + lr)      * K + lk;
    const u16* pb1l = bl + (size_t)(col0 + 16 + lr) * K + lk;

    f32x4 acc[2][2];
#pragma unroll
    for (int i = 0; i < 2; ++i)
#pragma unroll
        for (int j = 0; j < 2; ++j) acc[i][j] = (f32x4){0.f, 0.f, 0.f, 0.f};

#pragma unroll 2
    for (int k = 0; k < K; k += 32) {
        bf16x8 a0h = *(const bf16x8*)(pa0h + k);
        bf16x8 a1h = *(const bf16x8*)(pa1h + k);
        bf16x8 a0l = *(const bf16x8*)(pa0l + k);
        bf16x8 a1l = *(const bf16x8*)(pa1l + k);
        bf16x8 b0h = *(const bf16x8*)(pb0h + k);
        bf16x8 b1h = *(const bf16x8*)(pb1h + k);
        bf16x8 b0l = *(const bf16x8*)(pb0l + k);
        bf16x8 b1l = *(const bf16x8*)(pb1l + k);

        acc[0][0] = __builtin_amdgcn_mfma_f32_16x16x32_bf16(a0h, b0h, acc[0][0], 0, 0, 0);
        acc[0][1] = __builtin_amdgcn_mfma_f32_16x16x32_bf16(a0h, b1h, acc[0][1], 0, 0, 0);
        acc[1][0] = __builtin_amdgcn_mfma_f32_16x16x32_bf16(a1h, b0h, acc[1][0], 0, 0, 0);
        acc[1][1] = __builtin_amdgcn_mfma_f32_16x16x32_bf16(a1h, b1h, acc[1][1], 0, 0, 0);
        acc[0][0] = __builtin_amdgcn_mfma_f32_16x16x32_bf16(a0h, b0l, acc[0][0], 0, 0, 0);
        acc[0][1] = __builtin_amdgcn_mfma_f32_16x16x32_bf16(a0h, b1l, acc[0][1], 0, 0, 0);
        acc[1][0] = __builtin_amdgcn_mfma_f32_16x16x32_bf16(a1h, b0l, acc[1][0], 0, 0, 0);
        acc[1][1] = __builtin_amdgcn_mfma_f32_16x16x32_bf16(a1h, b1l, acc[1][1], 0, 0, 0);
        acc[0][0] = __builtin_amdgcn_mfma_f32_16x16x32_bf16(a0l, b0h, acc[0][0], 0, 0, 0);
        acc[0][1] = __builtin_amdgcn_mfma_f32_16x16x32_bf16(a0l, b1h, acc[0][1], 0, 0, 0);
        acc[1][0] = __builtin_amdgcn_mfma_f32_16x16x32_bf16(a1l, b0h, acc[1][0], 0, 0, 0);
        acc[1][1] = __builtin_amdgcn_mfma_f32_16x16x32_bf16(a1l, b1h, acc[1][1], 0, 0, 0);
    }

    int orq = (lane >> 4) * 4;
#pragma unroll
    for (int fm = 0; fm < 2; ++fm)
#pragma unroll
        for (int fn = 0; fn < 2; ++fn) {
            int ocg = head * 128 + col0 + fn * 16 + lr;
            float bb = bias[ocg];
#pragma unroll
            for (int i = 0; i < 4; ++i) {
                int orow = row0 + fm * 16 + orq + i;
                if (orow < N_NODES) {
                    float r = acc[fm][fn][i] + bb;
                    r = r > 0.0f ? r : expm1f(r);   // elu
                    u16 hh = f2bf(r);
                    outh[(size_t)orow * 512 + ocg] = hh;
                    outl[(size_t)orow * 512 + ocg] = f2bf(r - bf2f(hh));
                }
            }
        }
}

// ---------------------------------------------------------------------------
// Attention logits from a materialized h (gat2, H=1)
// ---------------------------------------------------------------------------
template<int H>
__global__ void att_kernel(const float* __restrict__ h,
                           const float* __restrict__ att_src,
                           const float* __restrict__ att_dst,
                           float* __restrict__ as, float* __restrict__ ad) {
    constexpr int EPL = 2 * H;
    constexpr int G   = 64 / H;
    int wv = threadIdx.x >> 6, lane = threadIdx.x & 63;
    int n = blockIdx.x * 4 + wv;
    const float* hp = h + (size_t)n * (H * 128) + lane * EPL;
    const float* sp = att_src + lane * EPL;
    const float* dp = att_dst + lane * EPL;
    float ss = 0.0f, sd = 0.0f;
#pragma unroll
    for (int i = 0; i < EPL; i += 2) {
        float2 v = *reinterpret_cast<const float2*>(hp + i);
        float2 a = *reinterpret_cast<const float2*>(sp + i);
        float2 b = *reinterpret_cast<const float2*>(dp + i);
        ss += v.x * a.x + v.y * a.y;
        sd += v.x * b.x + v.y * b.y;
    }
#pragma unroll
    for (int m = G >> 1; m > 0; m >>= 1) {
        ss += __shfl_xor(ss, m, 64);
        sd += __shfl_xor(sd, m, 64);
    }
    if ((lane & (G - 1)) == 0) {
        int hd = lane / G;
        as[(size_t)n * H + hd] = ss;
        ad[(size_t)n * H + hd] = sd;
    }
}

// ---------------------------------------------------------------------------
// CSR build (by dst)
// ---------------------------------------------------------------------------
__global__ void zero_int_kernel(int* __restrict__ p, int n) {
    int i = blockIdx.x * blockDim.x + threadIdx.x;
    if (i < n) p[i] = 0;
}

__global__ void deg_kernel(const int* __restrict__ ei, int* __restrict__ deg) {
    int e = blockIdx.x * blockDim.x + threadIdx.x;
    if (e >= ET) return;
    int d = (e < N_EDGES) ? ei[N_EDGES + e] : (e - N_EDGES);
    atomicAdd(&deg[d], 1);
}

__global__ void scan_kernel(const int* __restrict__ deg,
                            int* __restrict__ off, int* __restrict__ cur) {
    __shared__ int tmp[1024];
    __shared__ int carry;
    int tid = threadIdx.x;
    if (tid == 0) carry = 0;
    __syncthreads();
    for (int base = 0; base < N_NODES; base += 1024) {
        int i = base + tid;
        int v = (i < N_NODES) ? deg[i] : 0;
        tmp[tid] = v;
        __syncthreads();
        for (int s = 1; s < 1024; s <<= 1) {
            int t = (tid >= s) ? tmp[tid - s] : 0;
            __syncthreads();
            tmp[tid] += t;
            __syncthreads();
        }
        int incl = tmp[tid];
        int ex = carry + incl - v;
        if (i < N_NODES) { off[i] = ex; cur[i] = ex; }
        __syncthreads();
        if (tid == 1023) carry += incl;
        __syncthreads();
    }
    if (tid == 0) off[N_NODES] = carry;
}

__global__ void fill_kernel(const int* __restrict__ ei,
                            int* __restrict__ cur, int* __restrict__ csr_src) {
    int e = blockIdx.x * blockDim.x + threadIdx.x;
    if (e >= ET) return;
    int s, d;
    if (e < N_EDGES) { s = ei[e]; d = ei[N_EDGES + e]; }
    else             { s = e - N_EDGES; d = s; }
    int pos = atomicAdd(&cur[d], 1);
    csr_src[pos] = s;
}

// ---------------------------------------------------------------------------
// Segment softmax, wave-per-node
// ---------------------------------------------------------------------------
template<int H>
__global__ void softmax_kernel(const float* __restrict__ as,
                               const float* __restrict__ ad,
                               const int* __restrict__ off,
                               const int* __restrict__ csr_src,
                               float* __restrict__ exw,     // [ET, H]
                               float* __restrict__ inv_s) { // [N, H]
    int wv = threadIdx.x >> 6, lane = threadIdx.x & 63;
    int n = blockIdx.x * 4 + wv;
    int o0 = off[n], o1 = off[n + 1];
    float adn[H], m[H], s[H];
#pragma unroll
    for (int h = 0; h < H; ++h) { adn[h] = ad[(size_t)n * H + h]; m[h] = -1e30f; s[h] = 0.0f; }

    for (int j = o0 + lane; j < o1; j += 64) {
        int sn = csr_src[j];
#pragma unroll
        for (int h = 0; h < H; ++h) {
            float e = as[(size_t)sn * H + h] + adn[h];
            e = e > 0.0f ? e : 0.2f * e;
            m[h] = fmaxf(m[h], e);
        }
    }
#pragma unroll
    for (int mk = 32; mk > 0; mk >>= 1)
#pragma unroll
        for (int h = 0; h < H; ++h) m[h] = fmaxf(m[h], __shfl_xor(m[h], mk, 64));

    for (int j = o0 + lane; j < o1; j += 64) {
        int sn = csr_src[j];
        float exv[H];
#pragma unroll
        for (int h = 0; h < H; ++h) {
            float e = as[(size_t)sn * H + h] + adn[h];
            e = e > 0.0f ? e : 0.2f * e;
            exv[h] = expf(e - m[h]);
            s[h] += exv[h];
        }
        if (H == 4) {
            *reinterpret_cast<float4*>(exw + (size_t)j * 4) =
                make_float4(exv[0], exv[1], exv[2 % H], exv[3 % H]);
        } else {
            exw[j] = exv[0];
        }
    }
#pragma unroll
    for (int mk = 32; mk > 0; mk >>= 1)
#pragma unroll
        for (int h = 0; h < H; ++h) s[h] += __shfl_xor(s[h], mk, 64);

    if (lane == 0) {
#pragma unroll
        for (int h = 0; h < H; ++h) inv_s[(size_t)n * H + h] = 1.0f / (s[h] + 1e-16f);
    }
}

// ---------------------------------------------------------------------------
// gat1 pre-linear aggregation: aggx[head][n][c] =
//   inv_s[n,head] * sum_j exw[j,head] * xp[src_j, c]
// One node per block (512 thr: head = tid>>7, c = tid&127). Writes bf16 hi/lo.
// ---------------------------------------------------------------------------
__global__ void agg1_kernel(const float* __restrict__ xp,
                            const float* __restrict__ exw,
                            const float* __restrict__ inv_s,
                            const int* __restrict__ off,
                            const int* __restrict__ csr_src,
                            u16* __restrict__ aggh, u16* __restrict__ aggl) {
    int n = blockIdx.x;
    int c = threadIdx.x & 127, head = threadIdx.x >> 7;
    int o0 = off[n], o1 = off[n + 1];

    float acc = 0.0f;
    int j = o0;
    for (; j + 4 <= o1; j += 4) {
        int s0 = csr_src[j + 0], s1 = csr_src[j + 1];
        int s2 = csr_src[j + 2], s3 = csr_src[j + 3];
        float w0 = exw[(size_t)(j + 0) * 4 + head];
        float w1 = exw[(size_t)(j + 1) * 4 + head];
        float w2 = exw[(size_t)(j + 2) * 4 + head];
        float w3 = exw[(size_t)(j + 3) * 4 + head];
        float v0 = xp[(size_t)s0 * 128 + c];
        float v1 = xp[(size_t)s1 * 128 + c];
        float v2 = xp[(size_t)s2 * 128 + c];
        float v3 = xp[(size_t)s3 * 128 + c];
        acc = fmaf(w0, v0, acc);
        acc = fmaf(w1, v1, acc);
        acc = fmaf(w2, v2, acc);
        acc = fmaf(w3, v3, acc);
    }
    for (; j < o1; ++j) {
        int sn = csr_src[j];
        acc = fmaf(exw[(size_t)j * 4 + head], xp[(size_t)sn * 128 + c], acc);
    }

    float r = acc * inv_s[(size_t)n * 4 + head];
    u16 hh = f2bf(r);
    size_t o = ((size_t)head * PAD_N + n) * 128 + c;
    aggh[o] = hh;
    aggl[o] = f2bf(r - bf2f(hh));
}

// ---------------------------------------------------------------------------
// gat2 weighted gather (aggregate after linear; 128 ch):
// out = agg*inv + bias + beta*gp -> bf16 hi/lo
// ---------------------------------------------------------------------------
template<int NPB>
__global__ void gather2_kernel(const float* __restrict__ h,
                               const float* __restrict__ exw,
                               const float* __restrict__ inv_s,
                               const int* __restrict__ off,
                               const int* __restrict__ csr_src,
                               const float* __restrict__ bias,
                               u16* __restrict__ outh, u16* __restrict__ outl,
                               const float* __restrict__ gp,
                               const float* __restrict__ beta_p) {
    int sub = threadIdx.x >> 7;
    int c   = threadIdx.x & 127;
    int n   = blockIdx.x * NPB + sub;
    int o0 = off[n], o1 = off[n + 1];

    float acc = 0.0f;
    int j = o0;
    for (; j + 4 <= o1; j += 4) {
        int s0 = csr_src[j + 0], s1 = csr_src[j + 1];
        int s2 = csr_src[j + 2], s3 = csr_src[j + 3];
        float w0 = exw[j + 0], w1 = exw[j + 1];
        float w2 = exw[j + 2], w3 = exw[j + 3];
        float v0 = h[(size_t)s0 * 128 + c];
        float v1 = h[(size_t)s1 * 128 + c];
        float v2 = h[(size_t)s2 * 128 + c];
        float v3 = h[(size_t)s3 * 128 + c];
        acc = fmaf(w0, v0, acc);
        acc = fmaf(w1, v1, acc);
        acc = fmaf(w2, v2, acc);
        acc = fmaf(w3, v3, acc);
    }
    for (; j < o1; ++j) {
        acc = fmaf(exw[j], h[(size_t)csr_src[j] * 128 + c], acc);
    }

    float r = acc * inv_s[n] + bias[c] + beta_p[0] * gp[(size_t)n * 128 + c];
    u16 hh = f2bf(r);
    outh[(size_t)n * 128 + c] = hh;
    outl[(size_t)n * 128 + c] = f2bf(r - bf2f(hh));
}

// ---------------------------------------------------------------------------
extern "C" void kernel_launch(void* const* d_in, const int* in_sizes, int n_in,
                              void* d_out, int out_size, void* d_ws, size_t ws_size,
                              hipStream_t stream) {
    const float* x      = (const float*)d_in[0];
    const int*   ei     = (const int*)  d_in[1];
    const float* g      = (const float*)d_in[2];
    const float* proj_W = (const float*)d_in[3];
    const float* proj_b = (const float*)d_in[4];
    const float* gat1_W = (const float*)d_in[5];
    const float* g1_as  = (const float*)d_in[6];
    const float* g1_ad  = (const float*)d_in[7];
    const float* gat1_b = (const float*)d_in[8];
    const float* gat2_W = (const float*)d_in[9];
    const float* g2_as  = (const float*)d_in[10];
    const float* g2_ad  = (const float*)d_in[11];
    const float* gat2_b = (const float*)d_in[12];
    const float* dec_W  = (const float*)d_in[13];
    const float* dec_b  = (const float*)d_in[14];
    const float* beta   = (const float*)d_in[15];
    float* out = (float*)d_out;

    // ---- workspace carve ----
    char* p = (char*)d_ws;
    auto alloc = [&](size_t b) { void* r = (void*)p; p += (b + 255) & ~(size_t)255; return r; };
    u16*   abh  = (u16*)alloc((size_t)N_NODES * 768 * 2);   // x/g split; later helu hi
    u16*   abl  = (u16*)alloc((size_t)N_NODES * 768 * 2);   // x/g split; later helu lo
    float* xp   = (float*)alloc((size_t)PAD_N * 128 * 4);   // later h2
    float* gp   = (float*)alloc((size_t)PAD_N * 128 * 4);
    u16*   aggh = (u16*)alloc((size_t)4 * PAD_N * 128 * 2); // later hfin hi/lo
    u16*   aggl = (u16*)alloc((size_t)4 * PAD_N * 128 * 2);
    u16*   pwh  = (u16*)alloc(768 * 128 * 2);
    u16*   pwl  = (u16*)alloc(768 * 128 * 2);
    u16*   w1h  = (u16*)alloc(128 * 512 * 2);
    u16*   w1l  = (u16*)alloc(128 * 512 * 2);
    u16*   w2h  = (u16*)alloc(512 * 128 * 2);
    u16*   w2l  = (u16*)alloc(512 * 128 * 2);
    u16*   wdh  = (u16*)alloc(128 * 768 * 2);
    u16*   wdl  = (u16*)alloc(128 * 768 * 2);
    float* va1s = (float*)alloc(128 * 4 * 4);
    float* va1d = (float*)alloc(128 * 4 * 4);
    float* a1s  = (float*)alloc((size_t)N_NODES * 4 * 4);
    float* a1d  = (float*)alloc((size_t)N_NODES * 4 * 4);
    float* a2s  = (float*)alloc((size_t)N_NODES * 4);
    float* a2d  = (float*)alloc((size_t)N_NODES * 4);
    float* is1  = (float*)alloc((size_t)N_NODES * 4 * 4);
    float* is2  = (float*)alloc((size_t)N_NODES * 4);
    float* exw4 = (float*)alloc((size_t)ET * 4 * 4);
    float* exw1 = (float*)alloc((size_t)ET * 4);
    int*   deg  = (int*)alloc((size_t)N_NODES * 4);
    int*   off  = (int*)alloc((size_t)(N_NODES + 1) * 4);
    int*   cur  = (int*)alloc((size_t)N_NODES * 4);
    int*   csr  = (int*)alloc((size_t)ET * 4);
    // aliases (all stream-ordered: old use finishes before new write)
    u16*   heluh = abh;                                   // [PAD_N][512] bf16
    u16*   helul = abl;
    float* h2    = xp;                                    // [PAD_N][128] fp32
    u16*   hfinh = aggh;                                  // [PAD_N][128] bf16
    u16*   hfinl = aggh + (size_t)PAD_N * 128;

    const int GX = (N_NODES + 63) / 64;   // 157

    // ---- weight prep ----
    hipLaunchKernelGGL(wsplit_kernel, dim3((768 * 128 + 255) / 256), dim3(256), 0, stream,
                       proj_W, pwh, pwl, 768, 128);
    hipLaunchKernelGGL(wsplit_kernel, dim3((128 * 512 + 255) / 256), dim3(256), 0, stream,
                       gat1_W, w1h, w1l, 128, 512);
    hipLaunchKernelGGL(wsplit_kernel, dim3((512 * 128 + 255) / 256), dim3(256), 0, stream,
                       gat2_W, w2h, w2l, 512, 128);
    hipLaunchKernelGGL(wsplit_kernel, dim3((128 * 768 + 255) / 256), dim3(256), 0, stream,
                       dec_W, wdh, wdl, 128, 768);
    hipLaunchKernelGGL(va1_kernel, dim3(1), dim3(512), 0, stream,
                       gat1_W, g1_as, g1_ad, va1s, va1d);

    // ---- CSR build ----
    hipLaunchKernelGGL(zero_int_kernel, dim3((N_NODES + 255) / 256), dim3(256), 0, stream, deg, N_NODES);
    hipLaunchKernelGGL(deg_kernel, dim3((ET + 255) / 256), dim3(256), 0, stream, ei, deg);
    hipLaunchKernelGGL(scan_kernel, dim3(1), dim3(1024), 0, stream, deg, off, cur);
    hipLaunchKernelGGL(fill_kernel, dim3((ET + 255) / 256), dim3(256), 0, stream, ei, cur, csr);

    // ---- proj(x) -> xp fp32 ----
    hipLaunchKernelGGL(split_kernel, dim3(7500), dim3(256), 0, stream,
                       x, abh, abl, N_NODES * 768 / 4);
    hipLaunchKernelGGL((mm_kernel<768, 128, 0>), dim3(GX, 2), dim3(256), 0, stream,
                       abh, abl, pwh, pwl, proj_b,
                       xp, (u16*)nullptr, (u16*)nullptr, N_NODES - 1);

    // ---- proj(g) -> gp fp32 ----
    hipLaunchKernelGGL(split_kernel, dim3(7500), dim3(256), 0, stream,
                       g, abh, abl, N_NODES * 768 / 4);
    hipLaunchKernelGGL((mm_kernel<768, 128, 0>), dim3(GX, 2), dim3(256), 0, stream,
                       abh, abl, pwh, pwl, proj_b,
                       gp, (u16*)nullptr, (u16*)nullptr, N_NODES - 1);

    // ---- gat1: logits from xp (h1 never materialized) ----
    hipLaunchKernelGGL(att1_kernel, dim3(N_NODES / 4), dim3(256), 0, stream,
                       xp, va1s, va1d, a1s, a1d);
    hipLaunchKernelGGL(softmax_kernel<4>, dim3(N_NODES / 4), dim3(256), 0, stream,
                       a1s, a1d, off, csr, exw4, is1);
    hipLaunchKernelGGL(agg1_kernel, dim3(N_NODES), dim3(512), 0, stream,
                       xp, exw4, is1, off, csr, aggh, aggl);
    hipLaunchKernelGGL(mm_head_kernel, dim3(GX, 2, 4), dim3(256), 0, stream,
                       aggh, aggl, w1h, w1l, gat1_b, heluh, helul);

    // ---- gat2 ----
    hipLaunchKernelGGL((mm_kernel<512, 128, 0>), dim3(GX, 2), dim3(256), 0, stream,
                       heluh, helul, w2h, w2l, (const float*)nullptr,
                       h2, (u16*)nullptr, (u16*)nullptr, N_NODES - 1);
    hipLaunchKernelGGL(att_kernel<1>, dim3(N_NODES / 4), dim3(256), 0, stream,
                       h2, g2_as, g2_ad, a2s, a2d);
    hipLaunchKernelGGL(softmax_kernel<1>, dim3(N_NODES / 4), dim3(256), 0, stream,
                       a2s, a2d, off, csr, exw1, is2);
    hipLaunchKernelGGL((gather2_kernel<2>), dim3(N_NODES / 2), dim3(256), 0, stream,
                       h2, exw1, is2, off, csr, gat2_b, hfinh, hfinl, gp, beta);

    // ---- decoder ----
    hipLaunchKernelGGL((mm_kernel<128, 768, 0>), dim3(GX, 12), dim3(256), 0, stream,
                       hfinh, hfinl, wdh, wdl, dec_b,
                       out, (u16*)nullptr, (u16*)nullptr, N_NODES - 1);
}

// Round 5
// 316.782 us; speedup vs baseline: 1.1805x; 1.1805x over previous
//
#include <hip/hip_runtime.h>
#include <math.h>

#define N_NODES 10000
#define N_EDGES 160000
#define ET      (N_EDGES + N_NODES)   // with self loops

typedef unsigned short u16;
typedef __attribute__((ext_vector_type(8))) short bf16x8;
typedef __attribute__((ext_vector_type(4))) float f32x4;

__device__ __forceinline__ u16 f2bf(float f) {            // RNE (weights)
    union { float f; unsigned u; } v; v.f = f;
    unsigned r = (v.u + 0x7FFFu + ((v.u >> 16) & 1u)) >> 16;
    return (u16)r;
}
__device__ __forceinline__ float bf2f(u16 b) {
    union { unsigned u; float f; } v; v.u = ((unsigned)b) << 16;
    return v.f;
}

// in-register A split: 8 consecutive fp32 -> bf16 hi (trunc) + lo (exact resid)
__device__ __forceinline__ void splitA(const float* __restrict__ p,
                                       bf16x8& hv, bf16x8& lv) {
    float4 v0 = *reinterpret_cast<const float4*>(p);
    float4 v1 = *reinterpret_cast<const float4*>(p + 4);
    float f[8] = {v0.x, v0.y, v0.z, v0.w, v1.x, v1.y, v1.z, v1.w};
    bf16x8 h, l;
#pragma unroll
    for (int i = 0; i < 8; ++i) {
        unsigned u = __float_as_uint(f[i]);
        h[i] = (short)(u >> 16);
        float r = f[i] - __uint_as_float(u & 0xffff0000u);
        l[i] = (short)(__float_as_uint(r) >> 16);
    }
    hv = h; lv = l;
}

#define MFMA3(A_h, A_l, B_h, B_l, ACC)                                            \
    ACC = __builtin_amdgcn_mfma_f32_16x16x32_bf16(A_h, B_h, ACC, 0, 0, 0);        \
    ACC = __builtin_amdgcn_mfma_f32_16x16x32_bf16(A_h, B_l, ACC, 0, 0, 0);        \
    ACC = __builtin_amdgcn_mfma_f32_16x16x32_bf16(A_l, B_h, ACC, 0, 0, 0);

// ---------------------------------------------------------------------------
// all four weights: fp32 [K][N] -> transposed bf16 hi/lo [N][K], one launch
// ---------------------------------------------------------------------------
__global__ void wsplit_all_kernel(const float* __restrict__ W0, u16* o0h, u16* o0l,
                                  const float* __restrict__ W1, u16* o1h, u16* o1l,
                                  const float* __restrict__ W2, u16* o2h, u16* o2l,
                                  const float* __restrict__ W3, u16* o3h, u16* o3l) {
    int idx = blockIdx.x * blockDim.x + threadIdx.x;
    const float* W; u16 *oh, *ol; int N, rel;
    if (idx < 98304)       { W = W0; oh = o0h; ol = o0l; N = 128; rel = idx; }
    else if (idx < 163840) { W = W1; oh = o1h; ol = o1l; N = 512; rel = idx - 98304; }
    else if (idx < 229376) { W = W2; oh = o2h; ol = o2l; N = 128; rel = idx - 163840; }
    else if (idx < 327680) { W = W3; oh = o3h; ol = o3l; N = 768; rel = idx - 229376; }
    else return;
    int K = (N == 128) ? ((idx < 98304) ? 768 : 512) : 128;
    int k = rel / N, n = rel - k * N;
    float v = W[rel];
    u16 h = f2bf(v);
    oh[(size_t)n * K + k] = h;
    ol[(size_t)n * K + k] = f2bf(v - bf2f(h));
}

// ---------------------------------------------------------------------------
// va1[k][h] = sum_c W1[k, h*128+c] * att_src[h][c]  (and att_dst)
// ---------------------------------------------------------------------------
__global__ void va1_kernel(const float* __restrict__ W1,
                           const float* __restrict__ att_src,
                           const float* __restrict__ att_dst,
                           float* __restrict__ vas, float* __restrict__ vad) {
    int tid = threadIdx.x;
    int k = tid >> 2, h = tid & 3;
    float s = 0.0f, d = 0.0f;
    const float* wr = W1 + (size_t)k * 512 + h * 128;
    const float* as = att_src + h * 128;
    const float* ad = att_dst + h * 128;
    for (int c = 0; c < 128; ++c) {
        float w = wr[c];
        s = fmaf(w, as[c], s);
        d = fmaf(w, ad[c], d);
    }
    vas[k * 4 + h] = s;
    vad[k * 4 + h] = d;
}

// ---------------------------------------------------------------------------
// proj GEMM, split-K=3, x&g merged. grid (157, 6, 2); y = colTile + 2*sk.
// part[((src*3+sk)*10000 + n)*128 + c]  fp32
// ---------------------------------------------------------------------------
__global__ __launch_bounds__(256)
void proj_mm_kernel(const float* __restrict__ x, const float* __restrict__ g,
                    const u16* __restrict__ Bh, const u16* __restrict__ Bl,
                    float* __restrict__ part) {
    constexpr int K = 768;
    int src = blockIdx.z;
    int ct = blockIdx.y & 1, sk = blockIdx.y >> 1;
    const float* A = src ? g : x;
    int k0 = sk * 256;

    int lane = threadIdx.x & 63, wid = threadIdx.x >> 6;
    int wm = wid >> 1, wn = wid & 1;
    int row0 = blockIdx.x * 64 + wm * 32;
    int col0 = ct * 64 + wn * 32;
    int lr = lane & 15;
    int lk = (lane >> 4) * 8;

    int ra0 = min(row0 + lr,      N_NODES - 1);
    int ra1 = min(row0 + 16 + lr, N_NODES - 1);
    const float* pa0 = A + (size_t)ra0 * K + lk + k0;
    const float* pa1 = A + (size_t)ra1 * K + lk + k0;
    const u16* pb0h = Bh + (size_t)(col0 + lr)      * K + lk + k0;
    const u16* pb1h = Bh + (size_t)(col0 + 16 + lr) * K + lk + k0;
    const u16* pb0l = Bl + (size_t)(col0 + lr)      * K + lk + k0;
    const u16* pb1l = Bl + (size_t)(col0 + 16 + lr) * K + lk + k0;

    f32x4 acc[2][2];
#pragma unroll
    for (int i = 0; i < 2; ++i)
#pragma unroll
        for (int j = 0; j < 2; ++j) acc[i][j] = (f32x4){0.f, 0.f, 0.f, 0.f};

#pragma unroll 2
    for (int k = 0; k < 256; k += 32) {
        bf16x8 a0h, a0l, a1h, a1l;
        splitA(pa0 + k, a0h, a0l);
        splitA(pa1 + k, a1h, a1l);
        bf16x8 b0h = *(const bf16x8*)(pb0h + k);
        bf16x8 b1h = *(const bf16x8*)(pb1h + k);
        bf16x8 b0l = *(const bf16x8*)(pb0l + k);
        bf16x8 b1l = *(const bf16x8*)(pb1l + k);
        MFMA3(a0h, a0l, b0h, b0l, acc[0][0]);
        MFMA3(a0h, a0l, b1h, b1l, acc[0][1]);
        MFMA3(a1h, a1l, b0h, b0l, acc[1][0]);
        MFMA3(a1h, a1l, b1h, b1l, acc[1][1]);
    }

    float* pbase = part + (size_t)(src * 3 + sk) * 10000 * 128;
    int orq = (lane >> 4) * 4;
#pragma unroll
    for (int fm = 0; fm < 2; ++fm)
#pragma unroll
        for (int fn = 0; fn < 2; ++fn) {
            int oc = col0 + fn * 16 + lr;
#pragma unroll
            for (int i = 0; i < 4; ++i) {
                int orow = row0 + fm * 16 + orq + i;
                if (orow < N_NODES)
                    pbase[(size_t)orow * 128 + oc] = acc[fm][fn][i];
            }
        }
}

__global__ void proj_reduce_kernel(const float* __restrict__ part,
                                   const float* __restrict__ bias,
                                   float* __restrict__ xp, float* __restrict__ gp) {
    int i = blockIdx.x * blockDim.x + threadIdx.x;
    if (i >= 2 * 10000 * 32) return;
    int src = i / 320000;
    int r = i - src * 320000;
    const float4* p4 = reinterpret_cast<const float4*>(part) + (size_t)src * 3 * 320000;
    float4 a = p4[r], b = p4[320000 + r], c = p4[640000 + r];
    float4 bb = reinterpret_cast<const float4*>(bias)[r & 31];
    float4 o = make_float4(a.x + b.x + c.x + bb.x, a.y + b.y + c.y + bb.y,
                           a.z + b.z + c.z + bb.z, a.w + b.w + c.w + bb.w);
    reinterpret_cast<float4*>(src ? gp : xp)[r] = o;
}

// ---------------------------------------------------------------------------
// gat2 GEMM, split-K=4. grid (157, 8); y = colTile + 2*sk. A = helu fp32 [*,512]
// ---------------------------------------------------------------------------
__global__ __launch_bounds__(256)
void gat2_mm_kernel(const float* __restrict__ A,
                    const u16* __restrict__ Bh, const u16* __restrict__ Bl,
                    float* __restrict__ part) {
    constexpr int K = 512;
    int ct = blockIdx.y & 1, sk = blockIdx.y >> 1;
    int k0 = sk * 128;

    int lane = threadIdx.x & 63, wid = threadIdx.x >> 6;
    int wm = wid >> 1, wn = wid & 1;
    int row0 = blockIdx.x * 64 + wm * 32;
    int col0 = ct * 64 + wn * 32;
    int lr = lane & 15;
    int lk = (lane >> 4) * 8;

    int ra0 = min(row0 + lr,      N_NODES - 1);
    int ra1 = min(row0 + 16 + lr, N_NODES - 1);
    const float* pa0 = A + (size_t)ra0 * K + lk + k0;
    const float* pa1 = A + (size_t)ra1 * K + lk + k0;
    const u16* pb0h = Bh + (size_t)(col0 + lr)      * K + lk + k0;
    const u16* pb1h = Bh + (size_t)(col0 + 16 + lr) * K + lk + k0;
    const u16* pb0l = Bl + (size_t)(col0 + lr)      * K + lk + k0;
    const u16* pb1l = Bl + (size_t)(col0 + 16 + lr) * K + lk + k0;

    f32x4 acc[2][2];
#pragma unroll
    for (int i = 0; i < 2; ++i)
#pragma unroll
        for (int j = 0; j < 2; ++j) acc[i][j] = (f32x4){0.f, 0.f, 0.f, 0.f};

#pragma unroll 2
    for (int k = 0; k < 128; k += 32) {
        bf16x8 a0h, a0l, a1h, a1l;
        splitA(pa0 + k, a0h, a0l);
        splitA(pa1 + k, a1h, a1l);
        bf16x8 b0h = *(const bf16x8*)(pb0h + k);
        bf16x8 b1h = *(const bf16x8*)(pb1h + k);
        bf16x8 b0l = *(const bf16x8*)(pb0l + k);
        bf16x8 b1l = *(const bf16x8*)(pb1l + k);
        MFMA3(a0h, a0l, b0h, b0l, acc[0][0]);
        MFMA3(a0h, a0l, b1h, b1l, acc[0][1]);
        MFMA3(a1h, a1l, b0h, b0l, acc[1][0]);
        MFMA3(a1h, a1l, b1h, b1l, acc[1][1]);
    }

    float* pbase = part + (size_t)sk * 10000 * 128;
    int orq = (lane >> 4) * 4;
#pragma unroll
    for (int fm = 0; fm < 2; ++fm)
#pragma unroll
        for (int fn = 0; fn < 2; ++fn) {
            int oc = col0 + fn * 16 + lr;
#pragma unroll
            for (int i = 0; i < 4; ++i) {
                int orow = row0 + fm * 16 + orq + i;
                if (orow < N_NODES)
                    pbase[(size_t)orow * 128 + oc] = acc[fm][fn][i];
            }
        }
}

__global__ void gat2_reduce_kernel(const float* __restrict__ part,
                                   float* __restrict__ h2) {
    int r = blockIdx.x * blockDim.x + threadIdx.x;
    if (r >= 10000 * 32) return;
    const float4* p4 = reinterpret_cast<const float4*>(part);
    float4 a = p4[r], b = p4[320000 + r], c = p4[640000 + r], d = p4[960000 + r];
    reinterpret_cast<float4*>(h2)[r] =
        make_float4(a.x + b.x + c.x + d.x, a.y + b.y + c.y + d.y,
                    a.z + b.z + c.z + d.z, a.w + b.w + c.w + d.w);
}

// ---------------------------------------------------------------------------
// Unified K=128 GEMM (mm_head / decoder): A fp32 (in-reg split), B pre-split.
// grid (157, NT, NH): gcol0 = (z*NT + y)*64; A base = A + z*AHS.
// ACT 1: elu
// ---------------------------------------------------------------------------
template<int LDOUT, int NT, int ACT>
__global__ __launch_bounds__(256)
void mm128_kernel(const float* __restrict__ A, size_t ahs,
                  const u16* __restrict__ Bh, const u16* __restrict__ Bl,
                  const float* __restrict__ bias, float* __restrict__ out) {
    constexpr int K = 128;
    const float* a = A + (size_t)blockIdx.z * ahs;
    int lane = threadIdx.x & 63, wid = threadIdx.x >> 6;
    int wm = wid >> 1, wn = wid & 1;
    int row0 = blockIdx.x * 64 + wm * 32;
    int gcol0 = (blockIdx.z * NT + blockIdx.y) * 64 + wn * 32;
    int lr = lane & 15;
    int lk = (lane >> 4) * 8;

    int ra0 = min(row0 + lr,      N_NODES - 1);
    int ra1 = min(row0 + 16 + lr, N_NODES - 1);
    const float* pa0 = a + (size_t)ra0 * K + lk;
    const float* pa1 = a + (size_t)ra1 * K + lk;
    const u16* pb0h = Bh + (size_t)(gcol0 + lr)      * K + lk;
    const u16* pb1h = Bh + (size_t)(gcol0 + 16 + lr) * K + lk;
    const u16* pb0l = Bl + (size_t)(gcol0 + lr)      * K + lk;
    const u16* pb1l = Bl + (size_t)(gcol0 + 16 + lr) * K + lk;

    f32x4 acc[2][2];
#pragma unroll
    for (int i = 0; i < 2; ++i)
#pragma unroll
        for (int j = 0; j < 2; ++j) acc[i][j] = (f32x4){0.f, 0.f, 0.f, 0.f};

#pragma unroll 2
    for (int k = 0; k < K; k += 32) {
        bf16x8 a0h, a0l, a1h, a1l;
        splitA(pa0 + k, a0h, a0l);
        splitA(pa1 + k, a1h, a1l);
        bf16x8 b0h = *(const bf16x8*)(pb0h + k);
        bf16x8 b1h = *(const bf16x8*)(pb1h + k);
        bf16x8 b0l = *(const bf16x8*)(pb0l + k);
        bf16x8 b1l = *(const bf16x8*)(pb1l + k);
        MFMA3(a0h, a0l, b0h, b0l, acc[0][0]);
        MFMA3(a0h, a0l, b1h, b1l, acc[0][1]);
        MFMA3(a1h, a1l, b0h, b0l, acc[1][0]);
        MFMA3(a1h, a1l, b1h, b1l, acc[1][1]);
    }

    int orq = (lane >> 4) * 4;
#pragma unroll
    for (int fm = 0; fm < 2; ++fm)
#pragma unroll
        for (int fn = 0; fn < 2; ++fn) {
            int oc = gcol0 + fn * 16 + lr;
            float bb = bias[oc];
#pragma unroll
            for (int i = 0; i < 4; ++i) {
                int orow = row0 + fm * 16 + orq + i;
                if (orow < N_NODES) {
                    float r = acc[fm][fn][i] + bb;
                    if (ACT == 1) r = r > 0.0f ? r : expm1f(r);
                    out[(size_t)orow * LDOUT + oc] = r;
                }
            }
        }
}

// ---------------------------------------------------------------------------
// gat1 attention logits from xp
// ---------------------------------------------------------------------------
__global__ void att1_kernel(const float* __restrict__ xp,
                            const float* __restrict__ vas,
                            const float* __restrict__ vad,
                            float* __restrict__ as, float* __restrict__ ad) {
    int wv = threadIdx.x >> 6, lane = threadIdx.x & 63;
    int n = blockIdx.x * 4 + wv;
    float2 v = *reinterpret_cast<const float2*>(xp + (size_t)n * 128 + lane * 2);
    float4 s0 = *reinterpret_cast<const float4*>(vas + (lane * 2) * 4);
    float4 s1 = *reinterpret_cast<const float4*>(vas + (lane * 2 + 1) * 4);
    float4 d0 = *reinterpret_cast<const float4*>(vad + (lane * 2) * 4);
    float4 d1 = *reinterpret_cast<const float4*>(vad + (lane * 2 + 1) * 4);
    float ss[4] = { v.x * s0.x + v.y * s1.x, v.x * s0.y + v.y * s1.y,
                    v.x * s0.z + v.y * s1.z, v.x * s0.w + v.y * s1.w };
    float dd[4] = { v.x * d0.x + v.y * d1.x, v.x * d0.y + v.y * d1.y,
                    v.x * d0.z + v.y * d1.z, v.x * d0.w + v.y * d1.w };
#pragma unroll
    for (int m = 32; m > 0; m >>= 1)
#pragma unroll
        for (int h = 0; h < 4; ++h) {
            ss[h] += __shfl_xor(ss[h], m, 64);
            dd[h] += __shfl_xor(dd[h], m, 64);
        }
    if (lane == 0) {
#pragma unroll
        for (int h = 0; h < 4; ++h) {
            as[(size_t)n * 4 + h] = ss[h];
            ad[(size_t)n * 4 + h] = dd[h];
        }
    }
}

// ---------------------------------------------------------------------------
// gat2 attention logits (H=1)
// ---------------------------------------------------------------------------
__global__ void att2_kernel(const float* __restrict__ h,
                            const float* __restrict__ att_src,
                            const float* __restrict__ att_dst,
                            float* __restrict__ as, float* __restrict__ ad) {
    int wv = threadIdx.x >> 6, lane = threadIdx.x & 63;
    int n = blockIdx.x * 4 + wv;
    const float* hp = h + (size_t)n * 128 + lane * 2;
    float2 v = *reinterpret_cast<const float2*>(hp);
    float2 a = *reinterpret_cast<const float2*>(att_src + lane * 2);
    float2 b = *reinterpret_cast<const float2*>(att_dst + lane * 2);
    float ss = v.x * a.x + v.y * a.y;
    float sd = v.x * b.x + v.y * b.y;
#pragma unroll
    for (int m = 32; m > 0; m >>= 1) {
        ss += __shfl_xor(ss, m, 64);
        sd += __shfl_xor(sd, m, 64);
    }
    if (lane == 0) { as[n] = ss; ad[n] = sd; }
}

// ---------------------------------------------------------------------------
// CSR build (by dst)
// ---------------------------------------------------------------------------
__global__ void zero_int_kernel(int* __restrict__ p, int n) {
    int i = blockIdx.x * blockDim.x + threadIdx.x;
    if (i < n) p[i] = 0;
}

__global__ void deg_kernel(const int* __restrict__ ei, int* __restrict__ deg) {
    int e = blockIdx.x * blockDim.x + threadIdx.x;
    if (e >= ET) return;
    int d = (e < N_EDGES) ? ei[N_EDGES + e] : (e - N_EDGES);
    atomicAdd(&deg[d], 1);
}

__global__ void scan_kernel(const int* __restrict__ deg,
                            int* __restrict__ off, int* __restrict__ cur) {
    __shared__ int tmp[1024];
    __shared__ int carry;
    int tid = threadIdx.x;
    if (tid == 0) carry = 0;
    __syncthreads();
    for (int base = 0; base < N_NODES; base += 1024) {
        int i = base + tid;
        int v = (i < N_NODES) ? deg[i] : 0;
        tmp[tid] = v;
        __syncthreads();
        for (int s = 1; s < 1024; s <<= 1) {
            int t = (tid >= s) ? tmp[tid - s] : 0;
            __syncthreads();
            tmp[tid] += t;
            __syncthreads();
        }
        int incl = tmp[tid];
        int ex = carry + incl - v;
        if (i < N_NODES) { off[i] = ex; cur[i] = ex; }
        __syncthreads();
        if (tid == 1023) carry += incl;
        __syncthreads();
    }
    if (tid == 0) off[N_NODES] = carry;
}

__global__ void fill_kernel(const int* __restrict__ ei,
                            int* __restrict__ cur, int* __restrict__ csr_src) {
    int e = blockIdx.x * blockDim.x + threadIdx.x;
    if (e >= ET) return;
    int s, d;
    if (e < N_EDGES) { s = ei[e]; d = ei[N_EDGES + e]; }
    else             { s = e - N_EDGES; d = s; }
    int pos = atomicAdd(&cur[d], 1);
    csr_src[pos] = s;
}

// ---------------------------------------------------------------------------
// Segment softmax, wave-per-node
// ---------------------------------------------------------------------------
template<int H>
__global__ void softmax_kernel(const float* __restrict__ as,
                               const float* __restrict__ ad,
                               const int* __restrict__ off,
                               const int* __restrict__ csr_src,
                               float* __restrict__ exw,     // [ET, H]
                               float* __restrict__ inv_s) { // [N, H]
    int wv = threadIdx.x >> 6, lane = threadIdx.x & 63;
    int n = blockIdx.x * 4 + wv;
    int o0 = off[n], o1 = off[n + 1];
    float adn[H], m[H], s[H];
#pragma unroll
    for (int h = 0; h < H; ++h) { adn[h] = ad[(size_t)n * H + h]; m[h] = -1e30f; s[h] = 0.0f; }

    for (int j = o0 + lane; j < o1; j += 64) {
        int sn = csr_src[j];
#pragma unroll
        for (int h = 0; h < H; ++h) {
            float e = as[(size_t)sn * H + h] + adn[h];
            e = e > 0.0f ? e : 0.2f * e;
            m[h] = fmaxf(m[h], e);
        }
    }
#pragma unroll
    for (int mk = 32; mk > 0; mk >>= 1)
#pragma unroll
        for (int h = 0; h < H; ++h) m[h] = fmaxf(m[h], __shfl_xor(m[h], mk, 64));

    for (int j = o0 + lane; j < o1; j += 64) {
        int sn = csr_src[j];
        float exv[H];
#pragma unroll
        for (int h = 0; h < H; ++h) {
            float e = as[(size_t)sn * H + h] + adn[h];
            e = e > 0.0f ? e : 0.2f * e;
            exv[h] = expf(e - m[h]);
            s[h] += exv[h];
        }
        if (H == 4) {
            *reinterpret_cast<float4*>(exw + (size_t)j * 4) =
                make_float4(exv[0], exv[1], exv[2 % H], exv[3 % H]);
        } else {
            exw[j] = exv[0];
        }
    }
#pragma unroll
    for (int mk = 32; mk > 0; mk >>= 1)
#pragma unroll
        for (int h = 0; h < H; ++h) s[h] += __shfl_xor(s[h], mk, 64);

    if (lane == 0) {
#pragma unroll
        for (int h = 0; h < H; ++h) inv_s[(size_t)n * H + h] = 1.0f / (s[h] + 1e-16f);
    }
}

// ---------------------------------------------------------------------------
// gat1 pre-linear aggregation -> agg fp32 [head][10000][128]
// ---------------------------------------------------------------------------
__global__ void agg1_kernel(const float* __restrict__ xp,
                            const float* __restrict__ exw,
                            const float* __restrict__ inv_s,
                            const int* __restrict__ off,
                            const int* __restrict__ csr_src,
                            float* __restrict__ agg) {
    int n = blockIdx.x;
    int c = threadIdx.x & 127, head = threadIdx.x >> 7;
    int o0 = off[n], o1 = off[n + 1];

    float acc = 0.0f;
    int j = o0;
    for (; j + 4 <= o1; j += 4) {
        int s0 = csr_src[j + 0], s1 = csr_src[j + 1];
        int s2 = csr_src[j + 2], s3 = csr_src[j + 3];
        float w0 = exw[(size_t)(j + 0) * 4 + head];
        float w1 = exw[(size_t)(j + 1) * 4 + head];
        float w2 = exw[(size_t)(j + 2) * 4 + head];
        float w3 = exw[(size_t)(j + 3) * 4 + head];
        float v0 = xp[(size_t)s0 * 128 + c];
        float v1 = xp[(size_t)s1 * 128 + c];
        float v2 = xp[(size_t)s2 * 128 + c];
        float v3 = xp[(size_t)s3 * 128 + c];
        acc = fmaf(w0, v0, acc);
        acc = fmaf(w1, v1, acc);
        acc = fmaf(w2, v2, acc);
        acc = fmaf(w3, v3, acc);
    }
    for (; j < o1; ++j) {
        int sn = csr_src[j];
        acc = fmaf(exw[(size_t)j * 4 + head], xp[(size_t)sn * 128 + c], acc);
    }

    agg[((size_t)head * 10000 + n) * 128 + c] = acc * inv_s[(size_t)n * 4 + head];
}

// ---------------------------------------------------------------------------
// gat2 weighted gather -> hfin fp32 (+bias+beta*gp)
// ---------------------------------------------------------------------------
template<int NPB>
__global__ void gather2_kernel(const float* __restrict__ h,
                               const float* __restrict__ exw,
                               const float* __restrict__ inv_s,
                               const int* __restrict__ off,
                               const int* __restrict__ csr_src,
                               const float* __restrict__ bias,
                               float* __restrict__ outp,
                               const float* __restrict__ gp,
                               const float* __restrict__ beta_p) {
    int sub = threadIdx.x >> 7;
    int c   = threadIdx.x & 127;
    int n   = blockIdx.x * NPB + sub;
    int o0 = off[n], o1 = off[n + 1];

    float acc = 0.0f;
    int j = o0;
    for (; j + 4 <= o1; j += 4) {
        int s0 = csr_src[j + 0], s1 = csr_src[j + 1];
        int s2 = csr_src[j + 2], s3 = csr_src[j + 3];
        float w0 = exw[j + 0], w1 = exw[j + 1];
        float w2 = exw[j + 2], w3 = exw[j + 3];
        float v0 = h[(size_t)s0 * 128 + c];
        float v1 = h[(size_t)s1 * 128 + c];
        float v2 = h[(size_t)s2 * 128 + c];
        float v3 = h[(size_t)s3 * 128 + c];
        acc = fmaf(w0, v0, acc);
        acc = fmaf(w1, v1, acc);
        acc = fmaf(w2, v2, acc);
        acc = fmaf(w3, v3, acc);
    }
    for (; j < o1; ++j) {
        acc = fmaf(exw[j], h[(size_t)csr_src[j] * 128 + c], acc);
    }

    outp[(size_t)n * 128 + c] =
        acc * inv_s[n] + bias[c] + beta_p[0] * gp[(size_t)n * 128 + c];
}

// ---------------------------------------------------------------------------
extern "C" void kernel_launch(void* const* d_in, const int* in_sizes, int n_in,
                              void* d_out, int out_size, void* d_ws, size_t ws_size,
                              hipStream_t stream) {
    const float* x      = (const float*)d_in[0];
    const int*   ei     = (const int*)  d_in[1];
    const float* g      = (const float*)d_in[2];
    const float* proj_W = (const float*)d_in[3];
    const float* proj_b = (const float*)d_in[4];
    const float* gat1_W = (const float*)d_in[5];
    const float* g1_as  = (const float*)d_in[6];
    const float* g1_ad  = (const float*)d_in[7];
    const float* gat1_b = (const float*)d_in[8];
    const float* gat2_W = (const float*)d_in[9];
    const float* g2_as  = (const float*)d_in[10];
    const float* g2_ad  = (const float*)d_in[11];
    const float* gat2_b = (const float*)d_in[12];
    const float* dec_W  = (const float*)d_in[13];
    const float* dec_b  = (const float*)d_in[14];
    const float* beta   = (const float*)d_in[15];
    float* out = (float*)d_out;

    // ---- workspace carve (regions reused in stream order) ----
    char* p = (char*)d_ws;
    auto alloc = [&](size_t b) { void* r = (void*)p; p += (b + 255) & ~(size_t)255; return r; };
    // Region A (30.72 MB): proj partials [2][3][10000][128]f32 -> later helu [10000][512]f32
    float* ppart = (float*)alloc((size_t)2 * 3 * 10000 * 128 * 4);
    // Region B (20.48 MB): agg [4][10000][128]f32 -> gat2 partials [4][10000][128]f32 -> hfin
    float* rbig  = (float*)alloc((size_t)4 * 10000 * 128 * 4);
    float* xp    = (float*)alloc((size_t)10000 * 128 * 4);   // later h2
    float* gp    = (float*)alloc((size_t)10000 * 128 * 4);
    u16*   pwh   = (u16*)alloc(768 * 128 * 2);
    u16*   pwl   = (u16*)alloc(768 * 128 * 2);
    u16*   w1h   = (u16*)alloc(128 * 512 * 2);
    u16*   w1l   = (u16*)alloc(128 * 512 * 2);
    u16*   w2h   = (u16*)alloc(512 * 128 * 2);
    u16*   w2l   = (u16*)alloc(512 * 128 * 2);
    u16*   wdh   = (u16*)alloc(128 * 768 * 2);
    u16*   wdl   = (u16*)alloc(128 * 768 * 2);
    float* va1s  = (float*)alloc(128 * 4 * 4);
    float* va1d  = (float*)alloc(128 * 4 * 4);
    float* a1s   = (float*)alloc((size_t)N_NODES * 4 * 4);
    float* a1d   = (float*)alloc((size_t)N_NODES * 4 * 4);
    float* a2s   = (float*)alloc((size_t)N_NODES * 4);
    float* a2d   = (float*)alloc((size_t)N_NODES * 4);
    float* is1   = (float*)alloc((size_t)N_NODES * 4 * 4);
    float* is2   = (float*)alloc((size_t)N_NODES * 4);
    float* exw4  = (float*)alloc((size_t)ET * 4 * 4);
    float* exw1  = (float*)alloc((size_t)ET * 4);
    int*   deg   = (int*)alloc((size_t)N_NODES * 4);
    int*   off   = (int*)alloc((size_t)(N_NODES + 1) * 4);
    int*   cur   = (int*)alloc((size_t)N_NODES * 4);
    int*   csr   = (int*)alloc((size_t)ET * 4);
    // aliases
    float* helu  = ppart;   // [10000][512] f32, after proj_reduce
    float* agg   = rbig;    // [4][10000][128] f32
    float* gpart = rbig;    // [4][10000][128] f32, after mm_head
    float* hfin  = rbig;    // [10000][128] f32, after gat2_reduce
    float* h2    = xp;      // [10000][128] f32, after agg1/att1 done with xp

    const int GX = (N_NODES + 63) / 64;   // 157

    // ---- weight prep + CSR ----
    hipLaunchKernelGGL(wsplit_all_kernel, dim3(1280), dim3(256), 0, stream,
                       proj_W, pwh, pwl, gat1_W, w1h, w1l,
                       gat2_W, w2h, w2l, dec_W, wdh, wdl);
    hipLaunchKernelGGL(va1_kernel, dim3(1), dim3(512), 0, stream,
                       gat1_W, g1_as, g1_ad, va1s, va1d);
    hipLaunchKernelGGL(zero_int_kernel, dim3((N_NODES + 255) / 256), dim3(256), 0, stream, deg, N_NODES);
    hipLaunchKernelGGL(deg_kernel, dim3((ET + 255) / 256), dim3(256), 0, stream, ei, deg);
    hipLaunchKernelGGL(scan_kernel, dim3(1), dim3(1024), 0, stream, deg, off, cur);
    hipLaunchKernelGGL(fill_kernel, dim3((ET + 255) / 256), dim3(256), 0, stream, ei, cur, csr);

    // ---- proj (x & g, split-K=3) ----
    hipLaunchKernelGGL(proj_mm_kernel, dim3(GX, 6, 2), dim3(256), 0, stream,
                       x, g, pwh, pwl, ppart);
    hipLaunchKernelGGL(proj_reduce_kernel, dim3(2500), dim3(256), 0, stream,
                       ppart, proj_b, xp, gp);

    // ---- gat1 ----
    hipLaunchKernelGGL(att1_kernel, dim3(N_NODES / 4), dim3(256), 0, stream,
                       xp, va1s, va1d, a1s, a1d);
    hipLaunchKernelGGL(softmax_kernel<4>, dim3(N_NODES / 4), dim3(256), 0, stream,
                       a1s, a1d, off, csr, exw4, is1);
    hipLaunchKernelGGL(agg1_kernel, dim3(N_NODES), dim3(512), 0, stream,
                       xp, exw4, is1, off, csr, agg);
    hipLaunchKernelGGL((mm128_kernel<512, 2, 1>), dim3(GX, 2, 4), dim3(256), 0, stream,
                       agg, (size_t)10000 * 128, w1h, w1l, gat1_b, helu);

    // ---- gat2 (split-K=4) ----
    hipLaunchKernelGGL(gat2_mm_kernel, dim3(GX, 8, 1), dim3(256), 0, stream,
                       helu, w2h, w2l, gpart);
    hipLaunchKernelGGL(gat2_reduce_kernel, dim3(1250), dim3(256), 0, stream,
                       gpart, h2);
    hipLaunchKernelGGL(att2_kernel, dim3(N_NODES / 4), dim3(256), 0, stream,
                       h2, g2_as, g2_ad, a2s, a2d);
    hipLaunchKernelGGL(softmax_kernel<1>, dim3(N_NODES / 4), dim3(256), 0, stream,
                       a2s, a2d, off, csr, exw1, is2);
    hipLaunchKernelGGL((gather2_kernel<2>), dim3(N_NODES / 2), dim3(256), 0, stream,
                       h2, exw1, is2, off, csr, gat2_b, hfin, gp, beta);

    // ---- decoder ----
    hipLaunchKernelGGL((mm128_kernel<768, 12, 0>), dim3(GX, 12, 1), dim3(256), 0, stream,
                       hfin, (size_t)0, wdh, wdl, dec_b, out);
}

// Round 6
// 262.564 us; speedup vs baseline: 1.4243x; 1.2065x over previous
//
#include <hip/hip_runtime.h>
#include <math.h>

#define N_NODES 10000
#define N_EDGES 160000
#define ET      (N_EDGES + N_NODES)   // with self loops

typedef unsigned short u16;
typedef __attribute__((ext_vector_type(8))) short bf16x8;
typedef __attribute__((ext_vector_type(4))) float f32x4;

__device__ __forceinline__ u16 f2bf(float f) {            // RNE (weights)
    union { float f; unsigned u; } v; v.f = f;
    unsigned r = (v.u + 0x7FFFu + ((v.u >> 16) & 1u)) >> 16;
    return (u16)r;
}
__device__ __forceinline__ float bf2f(u16 b) {
    union { unsigned u; float f; } v; v.u = ((unsigned)b) << 16;
    return v.f;
}

// in-register A split: 8 consecutive fp32 -> bf16 hi (trunc) + lo (exact resid)
__device__ __forceinline__ void splitA8(const float* __restrict__ p,
                                        bf16x8& hv, bf16x8& lv) {
    float4 v0 = *reinterpret_cast<const float4*>(p);
    float4 v1 = *reinterpret_cast<const float4*>(p + 4);
    float f[8] = {v0.x, v0.y, v0.z, v0.w, v1.x, v1.y, v1.z, v1.w};
    bf16x8 h, l;
#pragma unroll
    for (int i = 0; i < 8; ++i) {
        unsigned u = __float_as_uint(f[i]);
        h[i] = (short)(u >> 16);
        float r = f[i] - __uint_as_float(u & 0xffff0000u);
        l[i] = (short)(__float_as_uint(r) >> 16);
    }
    hv = h; lv = l;
}

#define MFMA3(A_h, A_l, B_h, B_l, ACC)                                            \
    ACC = __builtin_amdgcn_mfma_f32_16x16x32_bf16(A_h, B_h, ACC, 0, 0, 0);        \
    ACC = __builtin_amdgcn_mfma_f32_16x16x32_bf16(A_h, B_l, ACC, 0, 0, 0);        \
    ACC = __builtin_amdgcn_mfma_f32_16x16x32_bf16(A_l, B_h, ACC, 0, 0, 0);

// async global->LDS, 16 B per lane, wave-uniform LDS base
#define GLD16(SRC, DST)                                                           \
    __builtin_amdgcn_global_load_lds(                                             \
        (const __attribute__((address_space(1))) void*)(SRC),                     \
        (__attribute__((address_space(3))) void*)(DST), 16, 0, 0)

// ---------------------------------------------------------------------------
// all four weights: fp32 [K][N] -> transposed bf16 hi/lo [N][K], one launch
// ---------------------------------------------------------------------------
__global__ void wsplit_all_kernel(const float* __restrict__ W0, u16* o0h, u16* o0l,
                                  const float* __restrict__ W1, u16* o1h, u16* o1l,
                                  const float* __restrict__ W2, u16* o2h, u16* o2l,
                                  const float* __restrict__ W3, u16* o3h, u16* o3l) {
    int idx = blockIdx.x * blockDim.x + threadIdx.x;
    const float* W; u16 *oh, *ol; int N, rel;
    if (idx < 98304)       { W = W0; oh = o0h; ol = o0l; N = 128; rel = idx; }
    else if (idx < 163840) { W = W1; oh = o1h; ol = o1l; N = 512; rel = idx - 98304; }
    else if (idx < 229376) { W = W2; oh = o2h; ol = o2l; N = 128; rel = idx - 163840; }
    else if (idx < 327680) { W = W3; oh = o3h; ol = o3l; N = 768; rel = idx - 229376; }
    else return;
    int K = (N == 128) ? ((idx < 98304) ? 768 : 512) : 128;
    int k = rel / N, n = rel - k * N;
    float v = W[rel];
    u16 h = f2bf(v);
    oh[(size_t)n * K + k] = h;
    ol[(size_t)n * K + k] = f2bf(v - bf2f(h));
}

// ---------------------------------------------------------------------------
// va1[k][h] = sum_c W1[k, h*128+c] * att_src[h][c]  (and att_dst)
// ---------------------------------------------------------------------------
__global__ void va1_kernel(const float* __restrict__ W1,
                           const float* __restrict__ att_src,
                           const float* __restrict__ att_dst,
                           float* __restrict__ vas, float* __restrict__ vad) {
    int tid = threadIdx.x;
    int k = tid >> 2, h = tid & 3;
    float s = 0.0f, d = 0.0f;
    const float* wr = W1 + (size_t)k * 512 + h * 128;
    const float* as = att_src + h * 128;
    const float* ad = att_dst + h * 128;
    for (int c = 0; c < 128; ++c) {
        float w = wr[c];
        s = fmaf(w, as[c], s);
        d = fmaf(w, ad[c], d);
    }
    vas[k * 4 + h] = s;
    vad[k * 4 + h] = d;
}

// ---------------------------------------------------------------------------
// Unified LDS-pipelined split-bf16 GEMM.
//   C[rows 10000, 128 cols per (y,z) tile] = A[rows][K] @ B^T + bias
// Block 256 thr = 4 waves side-by-side (each 32 rows x 32 cols = 2x2 frags).
// A fp32 staged async into LDS (double-buffered, BK=64), split in-reg.
// B bf16 hi/lo direct global (L2-hot), register double-buffered.
// LDS layout per tile: 8 ku-groups (8 k each) of [32 rows][8 floats] cells,
// group stride 1040 B (16-B pad) -> bank-balanced ds_read_b128.
// SRCSEL: z picks A0/A1 and out0/out1 (proj x&g). ZC: col base += z*ZC (heads).
// ---------------------------------------------------------------------------
template<int K, int SRCSEL, int ZC, int ACT, int LDOUT>
__global__ __launch_bounds__(256)
void mmT_kernel(const float* __restrict__ A0, const float* __restrict__ A1,
                size_t azs,
                const u16* __restrict__ Bh, const u16* __restrict__ Bl,
                const float* __restrict__ bias,
                float* __restrict__ out0, float* __restrict__ out1) {
    constexpr int NS = K / 64;
    __shared__ float smem[2 * 2080];           // 2 buffers x 8*260 floats
    const int lane = threadIdx.x & 63;
    const int wid  = threadIdx.x >> 6;
    const int lr = lane & 15, q = lane >> 4;
    const int row0 = blockIdx.x * 32;
    const int z = blockIdx.z;
    const int gcb = blockIdx.y * 128 + z * ZC;

    const float* Ab = SRCSEL ? (z ? A1 : A0) : (A0 + (size_t)z * azs);
    float* outp = (SRCSEL && z) ? out1 : out0;

    // staging: wave wid owns ku groups wid*2, wid*2+1; lane l -> row l>>1, half l&1
    const int srow = min(row0 + (lane >> 1), N_NODES - 1);
    const float* sA = Ab + (size_t)srow * K + (lane & 1) * 4;
    float* dg0 = smem + (wid * 2 + 0) * 260;
    float* dg1 = smem + (wid * 2 + 1) * 260;

    const u16* pbh[2]; const u16* pbl[2];
#pragma unroll
    for (int fn = 0; fn < 2; ++fn) {
        size_t br = (size_t)(gcb + wid * 32 + fn * 16 + lr) * K + q * 8;
        pbh[fn] = Bh + br; pbl[fn] = Bl + br;
    }

    f32x4 acc[2][2];
#pragma unroll
    for (int i = 0; i < 2; ++i)
#pragma unroll
        for (int j = 0; j < 2; ++j) acc[i][j] = (f32x4){0.f, 0.f, 0.f, 0.f};

    bf16x8 rbh[2][2][2], rbl[2][2][2];         // [bank][fn][ksub]

#define STAGE_T(BUF, S) do {                                                   \
        GLD16(sA + (S) * 64 + (wid * 2 + 0) * 8, dg0 + (BUF) * 2080);          \
        GLD16(sA + (S) * 64 + (wid * 2 + 1) * 8, dg1 + (BUF) * 2080);          \
    } while (0)

    // prologue: tile 0
    STAGE_T(0, 0);
#pragma unroll
    for (int fn = 0; fn < 2; ++fn)
#pragma unroll
        for (int ks = 0; ks < 2; ++ks) {
            rbh[0][fn][ks] = *(const bf16x8*)(pbh[fn] + ks * 32);
            rbl[0][fn][ks] = *(const bf16x8*)(pbl[fn] + ks * 32);
        }
    __syncthreads();

#pragma unroll
    for (int s = 0; s < NS; ++s) {
        const int bank = s & 1;
        if (s + 1 < NS) {
            STAGE_T(bank ^ 1, s + 1);
#pragma unroll
            for (int fn = 0; fn < 2; ++fn)
#pragma unroll
                for (int ks = 0; ks < 2; ++ks) {
                    rbh[bank ^ 1][fn][ks] = *(const bf16x8*)(pbh[fn] + (s + 1) * 64 + ks * 32);
                    rbl[bank ^ 1][fn][ks] = *(const bf16x8*)(pbl[fn] + (s + 1) * 64 + ks * 32);
                }
        }
        const float* lb = smem + bank * 2080;
        bf16x8 ah[2][2], al[2][2];             // [fm][ksub]
#pragma unroll
        for (int fm = 0; fm < 2; ++fm)
#pragma unroll
            for (int ks = 0; ks < 2; ++ks) {
                const float* fp = lb + (ks * 4 + q) * 260 + (fm * 16 + lr) * 8;
                splitA8(fp, ah[fm][ks], al[fm][ks]);
            }
#pragma unroll
        for (int fm = 0; fm < 2; ++fm)
#pragma unroll
            for (int fn = 0; fn < 2; ++fn)
#pragma unroll
                for (int ks = 0; ks < 2; ++ks) {
                    MFMA3(ah[fm][ks], al[fm][ks],
                          rbh[bank][fn][ks], rbl[bank][fn][ks], acc[fm][fn]);
                }
        __syncthreads();
    }

    int orq = q * 4;
#pragma unroll
    for (int fm = 0; fm < 2; ++fm)
#pragma unroll
        for (int fn = 0; fn < 2; ++fn) {
            int col = gcb + wid * 32 + fn * 16 + lr;
            float bb = bias ? bias[col] : 0.0f;
#pragma unroll
            for (int i = 0; i < 4; ++i) {
                int orow = row0 + fm * 16 + orq + i;
                if (orow < N_NODES) {
                    float r = acc[fm][fn][i] + bb;
                    if (ACT == 1) r = r > 0.0f ? r : expm1f(r);
                    outp[(size_t)orow * LDOUT + col] = r;
                }
            }
        }
#undef STAGE_T
}

// ---------------------------------------------------------------------------
// gat1 attention logits from xp
// ---------------------------------------------------------------------------
__global__ void att1_kernel(const float* __restrict__ xp,
                            const float* __restrict__ vas,
                            const float* __restrict__ vad,
                            float* __restrict__ as, float* __restrict__ ad) {
    int wv = threadIdx.x >> 6, lane = threadIdx.x & 63;
    int n = blockIdx.x * 4 + wv;
    float2 v = *reinterpret_cast<const float2*>(xp + (size_t)n * 128 + lane * 2);
    float4 s0 = *reinterpret_cast<const float4*>(vas + (lane * 2) * 4);
    float4 s1 = *reinterpret_cast<const float4*>(vas + (lane * 2 + 1) * 4);
    float4 d0 = *reinterpret_cast<const float4*>(vad + (lane * 2) * 4);
    float4 d1 = *reinterpret_cast<const float4*>(vad + (lane * 2 + 1) * 4);
    float ss[4] = { v.x * s0.x + v.y * s1.x, v.x * s0.y + v.y * s1.y,
                    v.x * s0.z + v.y * s1.z, v.x * s0.w + v.y * s1.w };
    float dd[4] = { v.x * d0.x + v.y * d1.x, v.x * d0.y + v.y * d1.y,
                    v.x * d0.z + v.y * d1.z, v.x * d0.w + v.y * d1.w };
#pragma unroll
    for (int m = 32; m > 0; m >>= 1)
#pragma unroll
        for (int h = 0; h < 4; ++h) {
            ss[h] += __shfl_xor(ss[h], m, 64);
            dd[h] += __shfl_xor(dd[h], m, 64);
        }
    if (lane == 0) {
#pragma unroll
        for (int h = 0; h < 4; ++h) {
            as[(size_t)n * 4 + h] = ss[h];
            ad[(size_t)n * 4 + h] = dd[h];
        }
    }
}

// ---------------------------------------------------------------------------
// gat2 attention logits (H=1)
// ---------------------------------------------------------------------------
__global__ void att2_kernel(const float* __restrict__ h,
                            const float* __restrict__ att_src,
                            const float* __restrict__ att_dst,
                            float* __restrict__ as, float* __restrict__ ad) {
    int wv = threadIdx.x >> 6, lane = threadIdx.x & 63;
    int n = blockIdx.x * 4 + wv;
    const float* hp = h + (size_t)n * 128 + lane * 2;
    float2 v = *reinterpret_cast<const float2*>(hp);
    float2 a = *reinterpret_cast<const float2*>(att_src + lane * 2);
    float2 b = *reinterpret_cast<const float2*>(att_dst + lane * 2);
    float ss = v.x * a.x + v.y * a.y;
    float sd = v.x * b.x + v.y * b.y;
#pragma unroll
    for (int m = 32; m > 0; m >>= 1) {
        ss += __shfl_xor(ss, m, 64);
        sd += __shfl_xor(sd, m, 64);
    }
    if (lane == 0) { as[n] = ss; ad[n] = sd; }
}

// ---------------------------------------------------------------------------
// CSR build (by dst)
// ---------------------------------------------------------------------------
__global__ void zero_int_kernel(int* __restrict__ p, int n) {
    int i = blockIdx.x * blockDim.x + threadIdx.x;
    if (i < n) p[i] = 0;
}

__global__ void deg_kernel(const int* __restrict__ ei, int* __restrict__ deg) {
    int e = blockIdx.x * blockDim.x + threadIdx.x;
    if (e >= ET) return;
    int d = (e < N_EDGES) ? ei[N_EDGES + e] : (e - N_EDGES);
    atomicAdd(&deg[d], 1);
}

__global__ void scan_kernel(const int* __restrict__ deg,
                            int* __restrict__ off, int* __restrict__ cur) {
    __shared__ int tmp[1024];
    __shared__ int carry;
    int tid = threadIdx.x;
    if (tid == 0) carry = 0;
    __syncthreads();
    for (int base = 0; base < N_NODES; base += 1024) {
        int i = base + tid;
        int v = (i < N_NODES) ? deg[i] : 0;
        tmp[tid] = v;
        __syncthreads();
        for (int s = 1; s < 1024; s <<= 1) {
            int t = (tid >= s) ? tmp[tid - s] : 0;
            __syncthreads();
            tmp[tid] += t;
            __syncthreads();
        }
        int incl = tmp[tid];
        int ex = carry + incl - v;
        if (i < N_NODES) { off[i] = ex; cur[i] = ex; }
        __syncthreads();
        if (tid == 1023) carry += incl;
        __syncthreads();
    }
    if (tid == 0) off[N_NODES] = carry;
}

__global__ void fill_kernel(const int* __restrict__ ei,
                            int* __restrict__ cur, int* __restrict__ csr_src) {
    int e = blockIdx.x * blockDim.x + threadIdx.x;
    if (e >= ET) return;
    int s, d;
    if (e < N_EDGES) { s = ei[e]; d = ei[N_EDGES + e]; }
    else             { s = e - N_EDGES; d = s; }
    int pos = atomicAdd(&cur[d], 1);
    csr_src[pos] = s;
}

// ---------------------------------------------------------------------------
// Segment softmax, wave-per-node
// ---------------------------------------------------------------------------
template<int H>
__global__ void softmax_kernel(const float* __restrict__ as,
                               const float* __restrict__ ad,
                               const int* __restrict__ off,
                               const int* __restrict__ csr_src,
                               float* __restrict__ exw,     // [ET, H]
                               float* __restrict__ inv_s) { // [N, H]
    int wv = threadIdx.x >> 6, lane = threadIdx.x & 63;
    int n = blockIdx.x * 4 + wv;
    int o0 = off[n], o1 = off[n + 1];
    float adn[H], m[H], s[H];
#pragma unroll
    for (int h = 0; h < H; ++h) { adn[h] = ad[(size_t)n * H + h]; m[h] = -1e30f; s[h] = 0.0f; }

    for (int j = o0 + lane; j < o1; j += 64) {
        int sn = csr_src[j];
#pragma unroll
        for (int h = 0; h < H; ++h) {
            float e = as[(size_t)sn * H + h] + adn[h];
            e = e > 0.0f ? e : 0.2f * e;
            m[h] = fmaxf(m[h], e);
        }
    }
#pragma unroll
    for (int mk = 32; mk > 0; mk >>= 1)
#pragma unroll
        for (int h = 0; h < H; ++h) m[h] = fmaxf(m[h], __shfl_xor(m[h], mk, 64));

    for (int j = o0 + lane; j < o1; j += 64) {
        int sn = csr_src[j];
        float exv[H];
#pragma unroll
        for (int h = 0; h < H; ++h) {
            float e = as[(size_t)sn * H + h] + adn[h];
            e = e > 0.0f ? e : 0.2f * e;
            exv[h] = expf(e - m[h]);
            s[h] += exv[h];
        }
        if (H == 4) {
            *reinterpret_cast<float4*>(exw + (size_t)j * 4) =
                make_float4(exv[0], exv[1], exv[2 % H], exv[3 % H]);
        } else {
            exw[j] = exv[0];
        }
    }
#pragma unroll
    for (int mk = 32; mk > 0; mk >>= 1)
#pragma unroll
        for (int h = 0; h < H; ++h) s[h] += __shfl_xor(s[h], mk, 64);

    if (lane == 0) {
#pragma unroll
        for (int h = 0; h < H; ++h) inv_s[(size_t)n * H + h] = 1.0f / (s[h] + 1e-16f);
    }
}

// ---------------------------------------------------------------------------
// gat1 pre-linear aggregation -> agg fp32 [head][10000][128]
// ---------------------------------------------------------------------------
__global__ void agg1_kernel(const float* __restrict__ xp,
                            const float* __restrict__ exw,
                            const float* __restrict__ inv_s,
                            const int* __restrict__ off,
                            const int* __restrict__ csr_src,
                            float* __restrict__ agg) {
    int n = blockIdx.x;
    int c = threadIdx.x & 127, head = threadIdx.x >> 7;
    int o0 = off[n], o1 = off[n + 1];

    float acc = 0.0f;
    int j = o0;
    for (; j + 4 <= o1; j += 4) {
        int s0 = csr_src[j + 0], s1 = csr_src[j + 1];
        int s2 = csr_src[j + 2], s3 = csr_src[j + 3];
        float w0 = exw[(size_t)(j + 0) * 4 + head];
        float w1 = exw[(size_t)(j + 1) * 4 + head];
        float w2 = exw[(size_t)(j + 2) * 4 + head];
        float w3 = exw[(size_t)(j + 3) * 4 + head];
        float v0 = xp[(size_t)s0 * 128 + c];
        float v1 = xp[(size_t)s1 * 128 + c];
        float v2 = xp[(size_t)s2 * 128 + c];
        float v3 = xp[(size_t)s3 * 128 + c];
        acc = fmaf(w0, v0, acc);
        acc = fmaf(w1, v1, acc);
        acc = fmaf(w2, v2, acc);
        acc = fmaf(w3, v3, acc);
    }
    for (; j < o1; ++j) {
        int sn = csr_src[j];
        acc = fmaf(exw[(size_t)j * 4 + head], xp[(size_t)sn * 128 + c], acc);
    }

    agg[((size_t)head * 10000 + n) * 128 + c] = acc * inv_s[(size_t)n * 4 + head];
}

// ---------------------------------------------------------------------------
// gat2 weighted gather -> hfin fp32 (+bias+beta*gp)
// ---------------------------------------------------------------------------
template<int NPB>
__global__ void gather2_kernel(const float* __restrict__ h,
                               const float* __restrict__ exw,
                               const float* __restrict__ inv_s,
                               const int* __restrict__ off,
                               const int* __restrict__ csr_src,
                               const float* __restrict__ bias,
                               float* __restrict__ outp,
                               const float* __restrict__ gp,
                               const float* __restrict__ beta_p) {
    int sub = threadIdx.x >> 7;
    int c   = threadIdx.x & 127;
    int n   = blockIdx.x * NPB + sub;
    int o0 = off[n], o1 = off[n + 1];

    float acc = 0.0f;
    int j = o0;
    for (; j + 4 <= o1; j += 4) {
        int s0 = csr_src[j + 0], s1 = csr_src[j + 1];
        int s2 = csr_src[j + 2], s3 = csr_src[j + 3];
        float w0 = exw[j + 0], w1 = exw[j + 1];
        float w2 = exw[j + 2], w3 = exw[j + 3];
        float v0 = h[(size_t)s0 * 128 + c];
        float v1 = h[(size_t)s1 * 128 + c];
        float v2 = h[(size_t)s2 * 128 + c];
        float v3 = h[(size_t)s3 * 128 + c];
        acc = fmaf(w0, v0, acc);
        acc = fmaf(w1, v1, acc);
        acc = fmaf(w2, v2, acc);
        acc = fmaf(w3, v3, acc);
    }
    for (; j < o1; ++j) {
        acc = fmaf(exw[j], h[(size_t)csr_src[j] * 128 + c], acc);
    }

    outp[(size_t)n * 128 + c] =
        acc * inv_s[n] + bias[c] + beta_p[0] * gp[(size_t)n * 128 + c];
}

// ---------------------------------------------------------------------------
extern "C" void kernel_launch(void* const* d_in, const int* in_sizes, int n_in,
                              void* d_out, int out_size, void* d_ws, size_t ws_size,
                              hipStream_t stream) {
    const float* x      = (const float*)d_in[0];
    const int*   ei     = (const int*)  d_in[1];
    const float* g      = (const float*)d_in[2];
    const float* proj_W = (const float*)d_in[3];
    const float* proj_b = (const float*)d_in[4];
    const float* gat1_W = (const float*)d_in[5];
    const float* g1_as  = (const float*)d_in[6];
    const float* g1_ad  = (const float*)d_in[7];
    const float* gat1_b = (const float*)d_in[8];
    const float* gat2_W = (const float*)d_in[9];
    const float* g2_as  = (const float*)d_in[10];
    const float* g2_ad  = (const float*)d_in[11];
    const float* gat2_b = (const float*)d_in[12];
    const float* dec_W  = (const float*)d_in[13];
    const float* dec_b  = (const float*)d_in[14];
    const float* beta   = (const float*)d_in[15];
    float* out = (float*)d_out;

    // ---- workspace carve (regions reused in stream order) ----
    char* p = (char*)d_ws;
    auto alloc = [&](size_t b) { void* r = (void*)p; p += (b + 255) & ~(size_t)255; return r; };
    float* helu = (float*)alloc((size_t)10000 * 512 * 4);      // 20.5 MB
    float* agg  = (float*)alloc((size_t)4 * 10000 * 128 * 4);  // 20.5 MB; hfin alias
    float* xp   = (float*)alloc((size_t)10000 * 128 * 4);      // h2 alias
    float* gp   = (float*)alloc((size_t)10000 * 128 * 4);
    u16*   pwh  = (u16*)alloc(768 * 128 * 2);
    u16*   pwl  = (u16*)alloc(768 * 128 * 2);
    u16*   w1h  = (u16*)alloc(128 * 512 * 2);
    u16*   w1l  = (u16*)alloc(128 * 512 * 2);
    u16*   w2h  = (u16*)alloc(512 * 128 * 2);
    u16*   w2l  = (u16*)alloc(512 * 128 * 2);
    u16*   wdh  = (u16*)alloc(128 * 768 * 2);
    u16*   wdl  = (u16*)alloc(128 * 768 * 2);
    float* va1s = (float*)alloc(128 * 4 * 4);
    float* va1d = (float*)alloc(128 * 4 * 4);
    float* a1s  = (float*)alloc((size_t)N_NODES * 4 * 4);
    float* a1d  = (float*)alloc((size_t)N_NODES * 4 * 4);
    float* a2s  = (float*)alloc((size_t)N_NODES * 4);
    float* a2d  = (float*)alloc((size_t)N_NODES * 4);
    float* is1  = (float*)alloc((size_t)N_NODES * 4 * 4);
    float* is2  = (float*)alloc((size_t)N_NODES * 4);
    float* exw4 = (float*)alloc((size_t)ET * 4 * 4);
    float* exw1 = (float*)alloc((size_t)ET * 4);
    int*   deg  = (int*)alloc((size_t)N_NODES * 4);
    int*   off  = (int*)alloc((size_t)(N_NODES + 1) * 4);
    int*   cur  = (int*)alloc((size_t)N_NODES * 4);
    int*   csr  = (int*)alloc((size_t)ET * 4);
    // aliases (stream-ordered reuse)
    float* h2   = xp;    // after att1/agg1 done with xp
    float* hfin = agg;   // after mm_head done with agg

    const int GR = (N_NODES + 31) / 32;   // 313 row-blocks

    // ---- weight prep + CSR ----
    hipLaunchKernelGGL(wsplit_all_kernel, dim3(1280), dim3(256), 0, stream,
                       proj_W, pwh, pwl, gat1_W, w1h, w1l,
                       gat2_W, w2h, w2l, dec_W, wdh, wdl);
    hipLaunchKernelGGL(va1_kernel, dim3(1), dim3(512), 0, stream,
                       gat1_W, g1_as, g1_ad, va1s, va1d);
    hipLaunchKernelGGL(zero_int_kernel, dim3((N_NODES + 255) / 256), dim3(256), 0, stream, deg, N_NODES);
    hipLaunchKernelGGL(deg_kernel, dim3((ET + 255) / 256), dim3(256), 0, stream, ei, deg);
    hipLaunchKernelGGL(scan_kernel, dim3(1), dim3(1024), 0, stream, deg, off, cur);
    hipLaunchKernelGGL(fill_kernel, dim3((ET + 255) / 256), dim3(256), 0, stream, ei, cur, csr);

    // ---- proj: xp = x@Wp+b, gp = g@Wp+b (z selects src; full K, no partials)
    hipLaunchKernelGGL((mmT_kernel<768, 1, 0, 0, 128>), dim3(GR, 1, 2), dim3(256), 0, stream,
                       x, g, (size_t)0, pwh, pwl, proj_b, xp, gp);

    // ---- gat1: logits from xp (h1 never materialized) ----
    hipLaunchKernelGGL(att1_kernel, dim3(N_NODES / 4), dim3(256), 0, stream,
                       xp, va1s, va1d, a1s, a1d);
    hipLaunchKernelGGL(softmax_kernel<4>, dim3(N_NODES / 4), dim3(256), 0, stream,
                       a1s, a1d, off, csr, exw4, is1);
    hipLaunchKernelGGL(agg1_kernel, dim3(N_NODES), dim3(512), 0, stream,
                       xp, exw4, is1, off, csr, agg);
    // per-head linear + bias + elu: helu[n, z*128+c]
    hipLaunchKernelGGL((mmT_kernel<128, 0, 128, 1, 512>), dim3(GR, 1, 4), dim3(256), 0, stream,
                       agg, (const float*)nullptr, (size_t)10000 * 128,
                       w1h, w1l, gat1_b, helu, (float*)nullptr);

    // ---- gat2 linear: h2 = helu @ W2 (full K=512) ----
    hipLaunchKernelGGL((mmT_kernel<512, 0, 0, 0, 128>), dim3(GR, 1, 1), dim3(256), 0, stream,
                       helu, (const float*)nullptr, (size_t)0,
                       w2h, w2l, (const float*)nullptr, h2, (float*)nullptr);
    hipLaunchKernelGGL(att2_kernel, dim3(N_NODES / 4), dim3(256), 0, stream,
                       h2, g2_as, g2_ad, a2s, a2d);
    hipLaunchKernelGGL(softmax_kernel<1>, dim3(N_NODES / 4), dim3(256), 0, stream,
                       a2s, a2d, off, csr, exw1, is2);
    hipLaunchKernelGGL((gather2_kernel<2>), dim3(N_NODES / 2), dim3(256), 0, stream,
                       h2, exw1, is2, off, csr, gat2_b, hfin, gp, beta);

    // ---- decoder: out = hfin @ Wd + b ----
    hipLaunchKernelGGL((mmT_kernel<128, 0, 0, 0, 768>), dim3(GR, 6, 1), dim3(256), 0, stream,
                       hfin, (const float*)nullptr, (size_t)0,
                       wdh, wdl, dec_b, out, (float*)nullptr);
}